// Round 1
// baseline (418.819 us; speedup 1.0000x reference)
//
#include <hip/hip_runtime.h>
#include <hip/hip_bf16.h>
#include <stdint.h>

// Problem dims
#define NE 8
#define NT 1024
#define NH 2048
#define NI 1408

typedef __attribute__((ext_vector_type(8))) short          bf16x8;
typedef __attribute__((ext_vector_type(8))) unsigned short u16x8;
typedef __attribute__((ext_vector_type(4))) float          f32x4;

__device__ __forceinline__ unsigned short f2bf(float f) {
  union { float f; uint32_t u; } v; v.f = f;
  uint32_t u = v.u;
  return (unsigned short)((u + 0x7FFFu + ((u >> 16) & 1u)) >> 16);  // RNE
}

// async global->LDS, 16B per lane. LDS dest is wave-uniform base + lane*16.
__device__ __forceinline__ void gload_lds16(const void* g, void* l) {
  __builtin_amdgcn_global_load_lds(
      (const __attribute__((address_space(1))) uint32_t*)g,
      (__attribute__((address_space(3))) uint32_t*)l, 16, 0, 0);
}

// ---------------------------------------------------------------------------
// Pre-pass: transpose + fp32->bf16.  src [E][R][C] f32  ->  dst [E][C][R] bf16
// ---------------------------------------------------------------------------
__global__ void transpose_cvt(const float* __restrict__ src,
                              unsigned short* __restrict__ dst,
                              int R, int C) {
  __shared__ float tile[32][33];  // +1 pad: no bank conflicts
  const int e  = blockIdx.z;
  const int c0 = blockIdx.x * 32;
  const int r0 = blockIdx.y * 32;
  const float* s = src + (size_t)e * R * C;
  unsigned short* d = dst + (size_t)e * R * C;
  const int tx = threadIdx.x, ty = threadIdx.y;  // (32,8)
  #pragma unroll
  for (int j = ty; j < 32; j += 8)
    tile[j][tx] = s[(size_t)(r0 + j) * C + c0 + tx];
  __syncthreads();
  #pragma unroll
  for (int j = ty; j < 32; j += 8)
    d[(size_t)(c0 + j) * R + r0 + tx] = f2bf(tile[tx][j]);
}

// ---------------------------------------------------------------------------
// GEMM A (fused gate+up):  h[e,t,i] = silu(x@Wg) * (x@Wu), bf16 out
// 128x128 tile, BK=32, 4 waves (2x2), 4x4 16x16 frags per wave per matrix.
// A (x, fp32) reg-staged with convert; Bg/Bu (bf16 [N][K]) via global_load_lds.
// ---------------------------------------------------------------------------
__global__ __launch_bounds__(256, 2) void gemm_gateup(
    const float* __restrict__ x,             // [E][T][H] f32
    const unsigned short* __restrict__ wgT,  // [E][I][H] bf16 (transposed)
    const unsigned short* __restrict__ wuT,  // [E][I][H] bf16
    unsigned short* __restrict__ hout) {     // [E][T][I] bf16
  __shared__ __align__(16) unsigned short As[128 * 32];
  __shared__ __align__(16) unsigned short Bg[128 * 32];
  __shared__ __align__(16) unsigned short Bu[128 * 32];

  const int e    = blockIdx.z;
  const int bm   = blockIdx.x * 128;  // T
  const int bn   = blockIdx.y * 128;  // I
  const int tid  = threadIdx.x;
  const int lane = tid & 63;
  const int w    = tid >> 6;
  const int wr   = (w >> 1) * 64;
  const int wc   = (w & 1) * 64;

  const float* xe = x + (size_t)e * NT * NH;
  const unsigned short* wge = wgT + (size_t)e * NI * NH;
  const unsigned short* wue = wuT + (size_t)e * NI * NH;

  f32x4 accg[4][4], accu[4][4];
  #pragma unroll
  for (int i = 0; i < 4; ++i)
    #pragma unroll
    for (int j = 0; j < 4; ++j) {
      accg[i][j] = f32x4{0.f, 0.f, 0.f, 0.f};
      accu[i][j] = f32x4{0.f, 0.f, 0.f, 0.f};
    }

  // A staging: thread covers row=tid>>1, 16 consecutive k at (tid&1)*16
  const int arow = tid >> 1;
  const int acol = (tid & 1) * 16;
  const float* asrc = xe + (size_t)(bm + arow) * NH + acol;

  // B staging (per wave, 2 chunks of 16 rows; lane covers row L>>2, col (L&3)*8)
  const int brow = lane >> 2;
  const int bcol = (lane & 3) * 8;

  // fragment addressing
  const int frow = lane & 15;
  const int fkb  = (lane >> 4) * 8;

  for (int k0 = 0; k0 < NH; k0 += 32) {
    {  // stage A fp32 -> bf16
      const float* s = asrc + k0;
      float4 f0 = *(const float4*)(s + 0);
      float4 f1 = *(const float4*)(s + 4);
      float4 f2 = *(const float4*)(s + 8);
      float4 f3 = *(const float4*)(s + 12);
      u16x8 p0, p1;
      p0[0]=f2bf(f0.x); p0[1]=f2bf(f0.y); p0[2]=f2bf(f0.z); p0[3]=f2bf(f0.w);
      p0[4]=f2bf(f1.x); p0[5]=f2bf(f1.y); p0[6]=f2bf(f1.z); p0[7]=f2bf(f1.w);
      p1[0]=f2bf(f2.x); p1[1]=f2bf(f2.y); p1[2]=f2bf(f2.z); p1[3]=f2bf(f2.w);
      p1[4]=f2bf(f3.x); p1[5]=f2bf(f3.y); p1[6]=f2bf(f3.z); p1[7]=f2bf(f3.w);
      *(u16x8*)(&As[arow * 32 + acol])     = p0;
      *(u16x8*)(&As[arow * 32 + acol + 8]) = p1;
    }
    #pragma unroll
    for (int q = 0; q < 2; ++q) {  // stage Bg/Bu (16B/lane, wave-uniform LDS base)
      const int rb = w * 32 + q * 16;
      const size_t gq = (size_t)(bn + rb + brow) * NH + k0 + bcol;
      gload_lds16(wge + gq, &Bg[rb * 32]);
      gload_lds16(wue + gq, &Bu[rb * 32]);
    }
    __syncthreads();

    bf16x8 af[4], bgf[4], bup[4];
    #pragma unroll
    for (int mi = 0; mi < 4; ++mi)
      af[mi] = *(const bf16x8*)(&As[(wr + mi * 16 + frow) * 32 + fkb]);
    #pragma unroll
    for (int ni = 0; ni < 4; ++ni) {
      bgf[ni] = *(const bf16x8*)(&Bg[(wc + ni * 16 + frow) * 32 + fkb]);
      bup[ni] = *(const bf16x8*)(&Bu[(wc + ni * 16 + frow) * 32 + fkb]);
    }
    #pragma unroll
    for (int mi = 0; mi < 4; ++mi)
      #pragma unroll
      for (int ni = 0; ni < 4; ++ni) {
        accg[mi][ni] = __builtin_amdgcn_mfma_f32_16x16x32_bf16(af[mi], bgf[ni], accg[mi][ni], 0, 0, 0);
        accu[mi][ni] = __builtin_amdgcn_mfma_f32_16x16x32_bf16(af[mi], bup[ni], accu[mi][ni], 0, 0, 0);
      }
    __syncthreads();
  }

  // epilogue: silu(g)*u -> bf16.  C/D frag: col=lane&15, row=(lane>>4)*4+j
  unsigned short* he = hout + (size_t)e * NT * NI;
  const int crow = (lane >> 4) * 4;
  const int ccol = lane & 15;
  #pragma unroll
  for (int mi = 0; mi < 4; ++mi)
    #pragma unroll
    for (int ni = 0; ni < 4; ++ni)
      #pragma unroll
      for (int j = 0; j < 4; ++j) {
        const float g = accg[mi][ni][j];
        const float u = accu[mi][ni][j];
        const float s = g / (1.0f + __expf(-g));
        const int row = bm + wr + mi * 16 + crow + j;
        const int col = bn + wc + ni * 16 + ccol;
        he[(size_t)row * NI + col] = f2bf(s * u);
      }
}

// ---------------------------------------------------------------------------
// GEMM B: out[e,t,h] = h[e,t,:] @ Wd[:,h]   (A=h bf16, B=WdT bf16, out fp32)
// ---------------------------------------------------------------------------
__global__ __launch_bounds__(256, 2) void gemm_down(
    const unsigned short* __restrict__ hbuf,  // [E][T][I] bf16
    const unsigned short* __restrict__ dT,    // [E][H][I] bf16 (transposed)
    float* __restrict__ out) {                // [E][T][H] f32
  __shared__ __align__(16) unsigned short As[128 * 32];
  __shared__ __align__(16) unsigned short Bs[128 * 32];

  const int e    = blockIdx.z;
  const int bm   = blockIdx.x * 128;  // T
  const int bn   = blockIdx.y * 128;  // H
  const int tid  = threadIdx.x;
  const int lane = tid & 63;
  const int w    = tid >> 6;
  const int wr   = (w >> 1) * 64;
  const int wc   = (w & 1) * 64;

  const unsigned short* he = hbuf + (size_t)e * NT * NI;
  const unsigned short* de = dT + (size_t)e * NH * NI;

  f32x4 acc[4][4];
  #pragma unroll
  for (int i = 0; i < 4; ++i)
    #pragma unroll
    for (int j = 0; j < 4; ++j) acc[i][j] = f32x4{0.f, 0.f, 0.f, 0.f};

  const int brow = lane >> 2;
  const int bcol = (lane & 3) * 8;
  const int frow = lane & 15;
  const int fkb  = (lane >> 4) * 8;

  for (int k0 = 0; k0 < NI; k0 += 32) {
    #pragma unroll
    for (int q = 0; q < 2; ++q) {
      const int rb = w * 32 + q * 16;
      gload_lds16(he + (size_t)(bm + rb + brow) * NI + k0 + bcol, &As[rb * 32]);
      gload_lds16(de + (size_t)(bn + rb + brow) * NI + k0 + bcol, &Bs[rb * 32]);
    }
    __syncthreads();

    bf16x8 af[4], bf[4];
    #pragma unroll
    for (int mi = 0; mi < 4; ++mi)
      af[mi] = *(const bf16x8*)(&As[(wr + mi * 16 + frow) * 32 + fkb]);
    #pragma unroll
    for (int ni = 0; ni < 4; ++ni)
      bf[ni] = *(const bf16x8*)(&Bs[(wc + ni * 16 + frow) * 32 + fkb]);
    #pragma unroll
    for (int mi = 0; mi < 4; ++mi)
      #pragma unroll
      for (int ni = 0; ni < 4; ++ni)
        acc[mi][ni] = __builtin_amdgcn_mfma_f32_16x16x32_bf16(af[mi], bf[ni], acc[mi][ni], 0, 0, 0);
    __syncthreads();
  }

  float* oe = out + (size_t)e * NT * NH;
  const int crow = (lane >> 4) * 4;
  const int ccol = lane & 15;
  #pragma unroll
  for (int mi = 0; mi < 4; ++mi)
    #pragma unroll
    for (int ni = 0; ni < 4; ++ni)
      #pragma unroll
      for (int j = 0; j < 4; ++j) {
        const int row = bm + wr + mi * 16 + crow + j;
        const int col = bn + wc + ni * 16 + ccol;
        oe[(size_t)row * NH + col] = acc[mi][ni][j];
      }
}

// ---------------------------------------------------------------------------
extern "C" void kernel_launch(void* const* d_in, const int* in_sizes, int n_in,
                              void* d_out, int out_size, void* d_ws, size_t ws_size,
                              hipStream_t stream) {
  const float* x    = (const float*)d_in[0];  // [E][T][H]
  const float* gate = (const float*)d_in[1];  // [E][H][I]
  const float* up   = (const float*)d_in[2];  // [E][H][I]
  const float* down = (const float*)d_in[3];  // [E][I][H]
  float* out = (float*)d_out;                 // [E][T][H]

  // workspace: wgT/wuT [E][I][H] bf16, dT [E][H][I] bf16, h [E][T][I] bf16
  // total = 3*46.1MB + 23.1MB = 161.5 MB
  unsigned short* wgT = (unsigned short*)d_ws;
  unsigned short* wuT = wgT + (size_t)NE * NI * NH;
  unsigned short* dT  = wuT + (size_t)NE * NI * NH;
  unsigned short* hb  = dT  + (size_t)NE * NI * NH;

  dim3 tb(32, 8);
  transpose_cvt<<<dim3(NI / 32, NH / 32, NE), tb, 0, stream>>>(gate, wgT, NH, NI);
  transpose_cvt<<<dim3(NI / 32, NH / 32, NE), tb, 0, stream>>>(up,   wuT, NH, NI);
  transpose_cvt<<<dim3(NH / 32, NI / 32, NE), tb, 0, stream>>>(down, dT,  NI, NH);

  gemm_gateup<<<dim3(NT / 128, NI / 128, NE), 256, 0, stream>>>(x, wgT, wuT, hb);
  gemm_down<<<dim3(NT / 128, NH / 128, NE), 256, 0, stream>>>(hb, dT, out);
}

// Round 2
// 391.039 us; speedup vs baseline: 1.0710x; 1.0710x over previous
//
#include <hip/hip_runtime.h>
#include <hip/hip_bf16.h>
#include <stdint.h>

// Problem dims
#define NE 8
#define NT 1024
#define NH 2048
#define NI 1408

typedef __attribute__((ext_vector_type(8))) short          bf16x8;
typedef __attribute__((ext_vector_type(8))) unsigned short u16x8;
typedef __attribute__((ext_vector_type(4))) unsigned short u16x4;
typedef __attribute__((ext_vector_type(4))) float          f32x4;

__device__ __forceinline__ unsigned short f2bf(float f) {
  union { float f; uint32_t u; } v; v.f = f;
  uint32_t u = v.u;
  return (unsigned short)((u + 0x7FFFu + ((u >> 16) & 1u)) >> 16);  // RNE
}

// async global->LDS, 16B per lane. LDS dest is wave-uniform base + lane*16.
__device__ __forceinline__ void gload_lds16(const void* g, void* l) {
  __builtin_amdgcn_global_load_lds(
      (const __attribute__((address_space(1))) uint32_t*)g,
      (__attribute__((address_space(3))) uint32_t*)l, 16, 0, 0);
}

// ---------------------------------------------------------------------------
// Pre-pass: transpose + fp32->bf16.  src [E][R][C] f32  ->  dst [E][C][R] bf16
// 64x64 tile, float4 loads, ushort4 stores. R,C multiples of 64.
// ---------------------------------------------------------------------------
__global__ __launch_bounds__(256) void transpose_cvt(
    const float* __restrict__ src, unsigned short* __restrict__ dst,
    int R, int C) {
  __shared__ float tile[64][65];
  const int e  = blockIdx.z;
  const int c0 = blockIdx.x * 64;
  const int r0 = blockIdx.y * 64;
  const float* s = src + (size_t)e * R * C;
  unsigned short* d = dst + (size_t)e * R * C;
  const int tid = threadIdx.x;
  const int tr  = tid >> 4;        // 0..15
  const int tc  = (tid & 15) * 4;  // 0..60
  #pragma unroll
  for (int it = 0; it < 4; ++it) {
    const int r = it * 16 + tr;
    float4 v = *(const float4*)(s + (size_t)(r0 + r) * C + c0 + tc);
    tile[r][tc + 0] = v.x; tile[r][tc + 1] = v.y;
    tile[r][tc + 2] = v.z; tile[r][tc + 3] = v.w;
  }
  __syncthreads();
  #pragma unroll
  for (int it = 0; it < 4; ++it) {
    const int oc = it * 16 + tr;  // tile column = output row offset
    u16x4 o;
    o[0] = f2bf(tile[tc + 0][oc]);
    o[1] = f2bf(tile[tc + 1][oc]);
    o[2] = f2bf(tile[tc + 2][oc]);
    o[3] = f2bf(tile[tc + 3][oc]);
    *(u16x4*)(d + (size_t)(c0 + oc) * R + r0 + tc) = o;
  }
}

// ---------------------------------------------------------------------------
// GEMM A (fused gate+up), 2-phase double-buffered.
// 128x128 tile, BK=32, 4 waves (2x2), 4x4 16x16 frags per wave per matrix.
// ---------------------------------------------------------------------------
struct AFetch { float4 f0, f1, f2, f3; };

__device__ __forceinline__ AFetch a_load(const float* p) {
  AFetch r;
  r.f0 = ((const float4*)p)[0];
  r.f1 = ((const float4*)p)[1];
  r.f2 = ((const float4*)p)[2];
  r.f3 = ((const float4*)p)[3];
  return r;
}

__device__ __forceinline__ void a_store(unsigned short* dstA, int arow, int acol,
                                        const AFetch& a) {
  u16x8 p0, p1;
  p0[0]=f2bf(a.f0.x); p0[1]=f2bf(a.f0.y); p0[2]=f2bf(a.f0.z); p0[3]=f2bf(a.f0.w);
  p0[4]=f2bf(a.f1.x); p0[5]=f2bf(a.f1.y); p0[6]=f2bf(a.f1.z); p0[7]=f2bf(a.f1.w);
  p1[0]=f2bf(a.f2.x); p1[1]=f2bf(a.f2.y); p1[2]=f2bf(a.f2.z); p1[3]=f2bf(a.f2.w);
  p1[4]=f2bf(a.f3.x); p1[5]=f2bf(a.f3.y); p1[6]=f2bf(a.f3.z); p1[7]=f2bf(a.f3.w);
  *(u16x8*)(&dstA[arow * 32 + acol])     = p0;
  *(u16x8*)(&dstA[arow * 32 + acol + 8]) = p1;
}

__device__ __forceinline__ void gu_step(
    const float* asrc, const unsigned short* wge, const unsigned short* wue,
    const unsigned short* Ac, const unsigned short* Bgc, const unsigned short* Buc,
    unsigned short* An, unsigned short* Bgn, unsigned short* Bun,
    int knext, bool pf,
    int arow, int acol, int bn, int w, int brow, int bcol,
    int wr, int wc, int frow, int fkb,
    f32x4 accg[4][4], f32x4 accu[4][4]) {
  AFetch a;
  if (pf) {
    a = a_load(asrc + knext);                      // issue A loads early
    #pragma unroll
    for (int q = 0; q < 2; ++q) {                  // issue B prefetch early
      const int rb = w * 32 + q * 16;
      const size_t gq = (size_t)(bn + rb + brow) * NH + knext + bcol;
      gload_lds16(wge + gq, Bgn + rb * 32);
      gload_lds16(wue + gq, Bun + rb * 32);
    }
  }
  bf16x8 af[4], bgf[4], buf_[4];
  #pragma unroll
  for (int mi = 0; mi < 4; ++mi)
    af[mi] = *(const bf16x8*)(&Ac[(wr + mi * 16 + frow) * 32 + fkb]);
  #pragma unroll
  for (int ni = 0; ni < 4; ++ni) {
    bgf[ni]  = *(const bf16x8*)(&Bgc[(wc + ni * 16 + frow) * 32 + fkb]);
    buf_[ni] = *(const bf16x8*)(&Buc[(wc + ni * 16 + frow) * 32 + fkb]);
  }
  #pragma unroll
  for (int mi = 0; mi < 4; ++mi)
    #pragma unroll
    for (int ni = 0; ni < 4; ++ni) {
      accg[mi][ni] = __builtin_amdgcn_mfma_f32_16x16x32_bf16(af[mi], bgf[ni],  accg[mi][ni], 0, 0, 0);
      accu[mi][ni] = __builtin_amdgcn_mfma_f32_16x16x32_bf16(af[mi], buf_[ni], accu[mi][ni], 0, 0, 0);
    }
  if (pf) a_store(An, arow, acol, a);              // convert+write after MFMA
  __syncthreads();                                 // one drain per K-step
}

__global__ __launch_bounds__(256, 2) void gemm_gateup(
    const float* __restrict__ x,             // [E][T][H] f32
    const unsigned short* __restrict__ wgT,  // [E][I][H] bf16
    const unsigned short* __restrict__ wuT,  // [E][I][H] bf16
    unsigned short* __restrict__ hout) {     // [E][T][I] bf16
  __shared__ __align__(16) unsigned short As0[128 * 32], As1[128 * 32];
  __shared__ __align__(16) unsigned short Bg0[128 * 32], Bg1[128 * 32];
  __shared__ __align__(16) unsigned short Bu0[128 * 32], Bu1[128 * 32];

  const int e    = blockIdx.z;
  const int bm   = blockIdx.x * 128;  // T
  const int bn   = blockIdx.y * 128;  // I
  const int tid  = threadIdx.x;
  const int lane = tid & 63;
  const int w    = tid >> 6;
  const int wr   = (w >> 1) * 64;
  const int wc   = (w & 1) * 64;

  const float* xe = x + (size_t)e * NT * NH;
  const unsigned short* wge = wgT + (size_t)e * NI * NH;
  const unsigned short* wue = wuT + (size_t)e * NI * NH;

  f32x4 accg[4][4], accu[4][4];
  #pragma unroll
  for (int i = 0; i < 4; ++i)
    #pragma unroll
    for (int j = 0; j < 4; ++j) {
      accg[i][j] = f32x4{0.f, 0.f, 0.f, 0.f};
      accu[i][j] = f32x4{0.f, 0.f, 0.f, 0.f};
    }

  const int arow = tid >> 1;
  const int acol = (tid & 1) * 16;
  const float* asrc = xe + (size_t)(bm + arow) * NH + acol;
  const int brow = lane >> 2;
  const int bcol = (lane & 3) * 8;
  const int frow = lane & 15;
  const int fkb  = (lane >> 4) * 8;

  // prologue: stage k=0 into buf0
  {
    AFetch a = a_load(asrc);
    a_store(As0, arow, acol, a);
    #pragma unroll
    for (int q = 0; q < 2; ++q) {
      const int rb = w * 32 + q * 16;
      const size_t gq = (size_t)(bn + rb + brow) * NH + bcol;
      gload_lds16(wge + gq, Bg0 + rb * 32);
      gload_lds16(wue + gq, Bu0 + rb * 32);
    }
  }
  __syncthreads();

  #pragma unroll 1
  for (int k0 = 0; k0 < NH - 64; k0 += 64) {
    gu_step(asrc, wge, wue, As0, Bg0, Bu0, As1, Bg1, Bu1, k0 + 32, true,
            arow, acol, bn, w, brow, bcol, wr, wc, frow, fkb, accg, accu);
    gu_step(asrc, wge, wue, As1, Bg1, Bu1, As0, Bg0, Bu0, k0 + 64, true,
            arow, acol, bn, w, brow, bcol, wr, wc, frow, fkb, accg, accu);
  }
  gu_step(asrc, wge, wue, As0, Bg0, Bu0, As1, Bg1, Bu1, NH - 32, true,
          arow, acol, bn, w, brow, bcol, wr, wc, frow, fkb, accg, accu);
  gu_step(asrc, wge, wue, As1, Bg1, Bu1, As0, Bg0, Bu0, 0, false,
          arow, acol, bn, w, brow, bcol, wr, wc, frow, fkb, accg, accu);

  // epilogue: silu(g)*u -> bf16.  C/D frag: col=lane&15, row=(lane>>4)*4+j
  unsigned short* he = hout + (size_t)e * NT * NI;
  const int crow = (lane >> 4) * 4;
  const int ccol = lane & 15;
  #pragma unroll
  for (int mi = 0; mi < 4; ++mi)
    #pragma unroll
    for (int ni = 0; ni < 4; ++ni)
      #pragma unroll
      for (int j = 0; j < 4; ++j) {
        const float g = accg[mi][ni][j];
        const float u = accu[mi][ni][j];
        const float s = g / (1.0f + __expf(-g));
        const int row = bm + wr + mi * 16 + crow + j;
        const int col = bn + wc + ni * 16 + ccol;
        he[(size_t)row * NI + col] = f2bf(s * u);
      }
}

// ---------------------------------------------------------------------------
// GEMM B: out[e,t,h] = h[e,t,:] @ Wd[:,h], 2-phase double-buffered.
// ---------------------------------------------------------------------------
__device__ __forceinline__ void dn_step(
    const unsigned short* he, const unsigned short* de,
    const unsigned short* Ac, const unsigned short* Bc,
    unsigned short* An, unsigned short* Bn,
    int knext, bool pf,
    int bm, int bn, int w, int brow, int bcol,
    int wr, int wc, int frow, int fkb, f32x4 acc[4][4]) {
  if (pf) {
    #pragma unroll
    for (int q = 0; q < 2; ++q) {
      const int rb = w * 32 + q * 16;
      gload_lds16(he + (size_t)(bm + rb + brow) * NI + knext + bcol, An + rb * 32);
      gload_lds16(de + (size_t)(bn + rb + brow) * NI + knext + bcol, Bn + rb * 32);
    }
  }
  bf16x8 af[4], bf[4];
  #pragma unroll
  for (int mi = 0; mi < 4; ++mi)
    af[mi] = *(const bf16x8*)(&Ac[(wr + mi * 16 + frow) * 32 + fkb]);
  #pragma unroll
  for (int ni = 0; ni < 4; ++ni)
    bf[ni] = *(const bf16x8*)(&Bc[(wc + ni * 16 + frow) * 32 + fkb]);
  #pragma unroll
  for (int mi = 0; mi < 4; ++mi)
    #pragma unroll
    for (int ni = 0; ni < 4; ++ni)
      acc[mi][ni] = __builtin_amdgcn_mfma_f32_16x16x32_bf16(af[mi], bf[ni], acc[mi][ni], 0, 0, 0);
  __syncthreads();
}

__global__ __launch_bounds__(256, 2) void gemm_down(
    const unsigned short* __restrict__ hbuf,  // [E][T][I] bf16
    const unsigned short* __restrict__ dT,    // [E][H][I] bf16
    float* __restrict__ out) {                // [E][T][H] f32
  __shared__ __align__(16) unsigned short As0[128 * 32], As1[128 * 32];
  __shared__ __align__(16) unsigned short Bs0[128 * 32], Bs1[128 * 32];

  const int e    = blockIdx.z;
  const int bm   = blockIdx.x * 128;  // T
  const int bn   = blockIdx.y * 128;  // H
  const int tid  = threadIdx.x;
  const int lane = tid & 63;
  const int w    = tid >> 6;
  const int wr   = (w >> 1) * 64;
  const int wc   = (w & 1) * 64;

  const unsigned short* he = hbuf + (size_t)e * NT * NI;
  const unsigned short* de = dT + (size_t)e * NH * NI;

  f32x4 acc[4][4];
  #pragma unroll
  for (int i = 0; i < 4; ++i)
    #pragma unroll
    for (int j = 0; j < 4; ++j) acc[i][j] = f32x4{0.f, 0.f, 0.f, 0.f};

  const int brow = lane >> 2;
  const int bcol = (lane & 3) * 8;
  const int frow = lane & 15;
  const int fkb  = (lane >> 4) * 8;

  // prologue
  {
    #pragma unroll
    for (int q = 0; q < 2; ++q) {
      const int rb = w * 32 + q * 16;
      gload_lds16(he + (size_t)(bm + rb + brow) * NI + bcol, As0 + rb * 32);
      gload_lds16(de + (size_t)(bn + rb + brow) * NI + bcol, Bs0 + rb * 32);
    }
  }
  __syncthreads();

  #pragma unroll 1
  for (int k0 = 0; k0 < NI - 64; k0 += 64) {
    dn_step(he, de, As0, Bs0, As1, Bs1, k0 + 32, true,
            bm, bn, w, brow, bcol, wr, wc, frow, fkb, acc);
    dn_step(he, de, As1, Bs1, As0, Bs0, k0 + 64, true,
            bm, bn, w, brow, bcol, wr, wc, frow, fkb, acc);
  }
  dn_step(he, de, As0, Bs0, As1, Bs1, NI - 32, true,
          bm, bn, w, brow, bcol, wr, wc, frow, fkb, acc);
  dn_step(he, de, As1, Bs1, As0, Bs0, 0, false,
          bm, bn, w, brow, bcol, wr, wc, frow, fkb, acc);

  float* oe = out + (size_t)e * NT * NH;
  const int crow = (lane >> 4) * 4;
  const int ccol = lane & 15;
  #pragma unroll
  for (int mi = 0; mi < 4; ++mi)
    #pragma unroll
    for (int ni = 0; ni < 4; ++ni)
      #pragma unroll
      for (int j = 0; j < 4; ++j) {
        const int row = bm + wr + mi * 16 + crow + j;
        const int col = bn + wc + ni * 16 + ccol;
        oe[(size_t)row * NH + col] = acc[mi][ni][j];
      }
}

// ---------------------------------------------------------------------------
extern "C" void kernel_launch(void* const* d_in, const int* in_sizes, int n_in,
                              void* d_out, int out_size, void* d_ws, size_t ws_size,
                              hipStream_t stream) {
  const float* x    = (const float*)d_in[0];  // [E][T][H]
  const float* gate = (const float*)d_in[1];  // [E][H][I]
  const float* up   = (const float*)d_in[2];  // [E][H][I]
  const float* down = (const float*)d_in[3];  // [E][I][H]
  float* out = (float*)d_out;                 // [E][T][H]

  unsigned short* wgT = (unsigned short*)d_ws;
  unsigned short* wuT = wgT + (size_t)NE * NI * NH;
  unsigned short* dT  = wuT + (size_t)NE * NI * NH;
  unsigned short* hb  = dT  + (size_t)NE * NI * NH;

  transpose_cvt<<<dim3(NI / 64, NH / 64, NE), 256, 0, stream>>>(gate, wgT, NH, NI);
  transpose_cvt<<<dim3(NI / 64, NH / 64, NE), 256, 0, stream>>>(up,   wuT, NH, NI);
  transpose_cvt<<<dim3(NH / 64, NI / 64, NE), 256, 0, stream>>>(down, dT,  NI, NH);

  gemm_gateup<<<dim3(NT / 128, NI / 128, NE), 256, 0, stream>>>(x, wgT, wuT, hb);
  gemm_down<<<dim3(NT / 128, NH / 128, NE), 256, 0, stream>>>(hb, dT, out);
}

// Round 3
// 334.654 us; speedup vs baseline: 1.2515x; 1.1685x over previous
//
#include <hip/hip_runtime.h>
#include <hip/hip_bf16.h>
#include <stdint.h>

// Problem dims
#define NE 8
#define NT 1024
#define NH 2048
#define NI 1408
#define NI2 (2 * NI)  // 2816

typedef __attribute__((ext_vector_type(8))) short          bf16x8;
typedef __attribute__((ext_vector_type(8))) unsigned short u16x8;
typedef __attribute__((ext_vector_type(4))) unsigned short u16x4;
typedef __attribute__((ext_vector_type(4))) float          f32x4;

__device__ __forceinline__ unsigned short f2bf(float f) {
  union { float f; uint32_t u; } v; v.f = f;
  uint32_t u = v.u;
  return (unsigned short)((u + 0x7FFFu + ((u >> 16) & 1u)) >> 16);  // RNE
}

// async global->LDS, 16B per lane. LDS dest is wave-uniform base + lane*16.
__device__ __forceinline__ void gload_lds16(const void* g, void* l) {
  __builtin_amdgcn_global_load_lds(
      (const __attribute__((address_space(1))) uint32_t*)g,
      (__attribute__((address_space(3))) uint32_t*)l, 16, 0, 0);
}

#define WAITV(n) asm volatile("s_waitcnt vmcnt(" #n ")" ::: "memory")
#define BAR() do { __builtin_amdgcn_sched_barrier(0); \
                   __builtin_amdgcn_s_barrier();      \
                   __builtin_amdgcn_sched_barrier(0); } while (0)

// ---------------------------------------------------------------------------
// x: fp32 -> bf16 elementwise
// ---------------------------------------------------------------------------
__global__ __launch_bounds__(256) void cvt_bf16(const float* __restrict__ src,
                                                unsigned short* __restrict__ dst,
                                                int n8) {
  int i = blockIdx.x * blockDim.x + threadIdx.x;
  const int stride = gridDim.x * blockDim.x;
  for (; i < n8; i += stride) {
    const float4 f0 = ((const float4*)src)[i * 2];
    const float4 f1 = ((const float4*)src)[i * 2 + 1];
    u16x8 o;
    o[0] = f2bf(f0.x); o[1] = f2bf(f0.y); o[2] = f2bf(f0.z); o[3] = f2bf(f0.w);
    o[4] = f2bf(f1.x); o[5] = f2bf(f1.y); o[6] = f2bf(f1.z); o[7] = f2bf(f1.w);
    ((u16x8*)dst)[i] = o;
  }
}

// ---------------------------------------------------------------------------
// Transpose + cvt:  src [E][R][C] f32  ->  dst rows mapped from c, ld = R, bf16
// ilv=1: out row = ((c>>4)<<5) | (c&15) | radd   (16-col gate/up interleave)
// ---------------------------------------------------------------------------
__global__ __launch_bounds__(256) void transpose_cvt(
    const float* __restrict__ src, unsigned short* __restrict__ dst,
    int R, int C, long estride, int ilv, int radd) {
  __shared__ float tile[64][65];
  const int e  = blockIdx.z;
  const int c0 = blockIdx.x * 64;
  const int r0 = blockIdx.y * 64;
  const float* s = src + (size_t)e * R * C;
  unsigned short* d = dst + (size_t)e * estride;
  const int tid = threadIdx.x;
  const int tr  = tid >> 4;        // 0..15
  const int tc  = (tid & 15) * 4;  // 0..60
  #pragma unroll
  for (int it = 0; it < 4; ++it) {
    const int r = it * 16 + tr;
    float4 v = *(const float4*)(s + (size_t)(r0 + r) * C + c0 + tc);
    tile[r][tc + 0] = v.x; tile[r][tc + 1] = v.y;
    tile[r][tc + 2] = v.z; tile[r][tc + 3] = v.w;
  }
  __syncthreads();
  #pragma unroll
  for (int it = 0; it < 4; ++it) {
    const int oc = it * 16 + tr;
    const int c  = c0 + oc;
    const int ro = ilv ? ((((c >> 4) << 5) | (c & 15)) | radd) : c;
    u16x4 o;
    o[0] = f2bf(tile[tc + 0][oc]);
    o[1] = f2bf(tile[tc + 1][oc]);
    o[2] = f2bf(tile[tc + 2][oc]);
    o[3] = f2bf(tile[tc + 3][oc]);
    *(u16x4*)(d + (size_t)ro * R + r0 + tc) = o;
  }
}

// ---------------------------------------------------------------------------
// Pipelined GEMM: C[e,m,n] = A[e,m,:] . B[e,n,:]   (both bf16, K-contiguous)
// BM=128, BN=256, BK=64, 512 threads (8 waves, 2M x 4N), triple-buffered LDS,
// counted vmcnt (12/6/0), T2 XOR-swizzle via pre-swizzled global source.
// MODE 0: plain f32 out [E][1024][NBY*256]
// MODE 1: silu-pair bf16 out [E][1024][NBY*128]  (B cols interleaved g16/u16)
// ---------------------------------------------------------------------------
template <int NBY, int KDIM, int MODE>
__global__ __launch_bounds__(512, 2) void gemm_pipe(
    const unsigned short* __restrict__ Ag,  // [E][1024][KDIM]
    const unsigned short* __restrict__ Bg,  // [E][NBY*256][KDIM]
    void* __restrict__ outp) {
  constexpr int KSTEPS = KDIM / 64;
  constexpr int NBLK   = NE * NBY * 8;
  constexpr int CHUNK  = NBLK / 8;

  __shared__ __align__(16) unsigned short As[3][128 * 64];
  __shared__ __align__(16) unsigned short Bs[3][256 * 64];

  // XCD-chunked bijective swizzle (one expert per XCD chunk)
  const int flat = blockIdx.x;
  const int orig = (flat & 7) * CHUNK + (flat >> 3);
  const int bx   = orig & 7;
  const int rest = orig >> 3;
  const int by   = rest % NBY;
  const int e    = rest / NBY;

  const int bm  = bx * 128;
  const int bnn = by * 256;

  const int tid  = threadIdx.x;
  const int lane = tid & 63;
  const int w    = tid >> 6;
  const int wrm  = (w >> 2) * 64;  // wave M offset
  const int wcn  = (w & 3) * 64;   // wave N offset

  const unsigned short* Ae = Ag + (size_t)e * 1024 * KDIM;
  const unsigned short* Be = Bg + (size_t)e * (NBY * 256) * KDIM;

  // staging: per gload_lds call a wave covers 8 rows x 128B; lane l handles
  // row l>>3, 16B chunk (l&7). Pre-swizzle global source chunk: j' = j ^ row7.
  const int l8 = lane >> 3;
  const int jx = (lane & 7) ^ l8;
  const unsigned short* aAg = Ae + (size_t)(bm  + w * 16 + l8) * KDIM + jx * 8;
  const unsigned short* aBg = Be + (size_t)(bnn + w * 32 + l8) * KDIM + jx * 8;

  f32x4 acc[4][4];
  #pragma unroll
  for (int i = 0; i < 4; ++i)
    #pragma unroll
    for (int j = 0; j < 4; ++j) acc[i][j] = f32x4{0.f, 0.f, 0.f, 0.f};

  // swizzled fragment read offset (bytes): row'=lane&15 within 16-row frag,
  // col bytes = kk*64 + (lane>>4)*16, XOR (row&7)<<4
  const int aoff = (lane & 15) * 128 + ((((lane >> 4) << 4)) ^ ((lane & 7) << 4));

  auto STAGE = [&](unsigned short* Ad, unsigned short* Bd, int kstep) {
    const int kb = kstep * 64;
    #pragma unroll
    for (int q = 0; q < 2; ++q)
      gload_lds16(aAg + (size_t)q * 8 * KDIM + kb, Ad + (w * 16 + q * 8) * 64);
    #pragma unroll
    for (int q = 0; q < 4; ++q)
      gload_lds16(aBg + (size_t)q * 8 * KDIM + kb, Bd + (w * 32 + q * 8) * 64);
  };

  auto COMPUTE = [&](const unsigned short* Ab_, const unsigned short* Bb_) {
    const char* Ab = (const char*)Ab_ + wrm * 128;
    const char* Bb = (const char*)Bb_ + wcn * 128;
    bf16x8 af[4][2], bf[4][2];
    #pragma unroll
    for (int mi = 0; mi < 4; ++mi) {
      af[mi][0] = *(const bf16x8*)(Ab + mi * 2048 + aoff);
      af[mi][1] = *(const bf16x8*)(Ab + mi * 2048 + (aoff ^ 64));
    }
    #pragma unroll
    for (int nj = 0; nj < 4; ++nj) {
      bf[nj][0] = *(const bf16x8*)(Bb + nj * 2048 + aoff);
      bf[nj][1] = *(const bf16x8*)(Bb + nj * 2048 + (aoff ^ 64));
    }
    __builtin_amdgcn_s_setprio(1);
    #pragma unroll
    for (int kk = 0; kk < 2; ++kk)
      #pragma unroll
      for (int mi = 0; mi < 4; ++mi)
        #pragma unroll
        for (int nj = 0; nj < 4; ++nj)
          acc[mi][nj] = __builtin_amdgcn_mfma_f32_16x16x32_bf16(
              af[mi][kk], bf[nj][kk], acc[mi][nj], 0, 0, 0);
    __builtin_amdgcn_s_setprio(0);
  };

  unsigned short *a0 = As[0], *a1 = As[1], *a2 = As[2];
  unsigned short *b0 = Bs[0], *b1 = Bs[1], *b2 = Bs[2];

  // prologue: stage steps 0,1
  STAGE(a0, b0, 0);
  STAGE(a1, b1, 1);

  #pragma unroll 1
  for (int s = 0; s < KSTEPS; ++s) {
    if (s + 2 < KSTEPS) {
      STAGE(a2, b2, s + 2);
      WAITV(12);          // own loads for step s retired; s+1,s+2 in flight
    } else if (s + 2 == KSTEPS) {
      WAITV(6);
    } else {
      WAITV(0);
    }
    BAR();                // all waves' step-s data visible
    COMPUTE(a0, b0);
    BAR();                // all waves done reading slot s before restage
    unsigned short* t;
    t = a0; a0 = a1; a1 = a2; a2 = t;
    t = b0; b0 = b1; b1 = b2; b2 = t;
  }

  const int crow = (lane >> 4) * 4;
  const int ccol = lane & 15;
  if constexpr (MODE == 0) {
    float* oe = (float*)outp + (size_t)e * 1024 * (NBY * 256);
    #pragma unroll
    for (int mi = 0; mi < 4; ++mi)
      #pragma unroll
      for (int nj = 0; nj < 4; ++nj)
        #pragma unroll
        for (int j = 0; j < 4; ++j) {
          const int row = bm + wrm + mi * 16 + crow + j;
          const int col = bnn + wcn + nj * 16 + ccol;
          oe[(size_t)row * (NBY * 256) + col] = acc[mi][nj][j];
        }
  } else {
    // silu-pair: frag nj=2p is gate cols, nj=2p+1 the matching up cols
    unsigned short* he = (unsigned short*)outp + (size_t)e * 1024 * (NBY * 128);
    const int hcb = by * 128 + (wcn >> 1);
    #pragma unroll
    for (int mi = 0; mi < 4; ++mi)
      #pragma unroll
      for (int p = 0; p < 2; ++p)
        #pragma unroll
        for (int j = 0; j < 4; ++j) {
          const float g = acc[mi][2 * p][j];
          const float u = acc[mi][2 * p + 1][j];
          const float sv = g / (1.0f + __expf(-g)) * u;
          const int row = bm + wrm + mi * 16 + crow + j;
          const int col = hcb + p * 16 + ccol;
          he[(size_t)row * (NBY * 128) + col] = f2bf(sv);
        }
  }
}

// ---------------------------------------------------------------------------
extern "C" void kernel_launch(void* const* d_in, const int* in_sizes, int n_in,
                              void* d_out, int out_size, void* d_ws, size_t ws_size,
                              hipStream_t stream) {
  const float* x    = (const float*)d_in[0];  // [E][T][H]
  const float* gate = (const float*)d_in[1];  // [E][H][I]
  const float* up   = (const float*)d_in[2];  // [E][H][I]
  const float* down = (const float*)d_in[3];  // [E][I][H]
  float* out = (float*)d_out;                 // [E][T][H]

  // workspace (bf16 elems): x_bf [E][T][H], wcat [E][2I][H] (interleaved 16-col
  // gate/up), dT [E][H][I], h [E][T][I].  Total ~186 MiB.
  unsigned short* x_bf = (unsigned short*)d_ws;
  unsigned short* wcat = x_bf + (size_t)NE * NT * NH;
  unsigned short* dT   = wcat + (size_t)NE * NI2 * NH;
  unsigned short* hb   = dT   + (size_t)NE * NH * NI;

  cvt_bf16<<<2048, 256, 0, stream>>>(x, x_bf, NE * NT * NH / 8);

  transpose_cvt<<<dim3(NI / 64, NH / 64, NE), 256, 0, stream>>>(
      gate, wcat, NH, NI, (long)NI2 * NH, 1, 0);
  transpose_cvt<<<dim3(NI / 64, NH / 64, NE), 256, 0, stream>>>(
      up, wcat, NH, NI, (long)NI2 * NH, 1, 16);
  transpose_cvt<<<dim3(NH / 64, NI / 64, NE), 256, 0, stream>>>(
      down, dT, NI, NH, (long)NH * NI, 0, 0);

  // GEMM1: [1024 x 2816] = x_bf @ wcat^T, fused silu-pair -> h bf16
  gemm_pipe<11, NH, 1><<<NE * 11 * 8, 512, 0, stream>>>(x_bf, wcat, hb);
  // GEMM2: [1024 x 2048] = h @ dT^T -> out f32
  gemm_pipe<8, NI, 0><<<NE * 8 * 8, 512, 0, stream>>>(hb, dT, out);
}

// Round 4
// 274.845 us; speedup vs baseline: 1.5238x; 1.2176x over previous
//
#include <hip/hip_runtime.h>
#include <hip/hip_bf16.h>
#include <stdint.h>

// Problem dims
#define NE 8
#define NT 1024
#define NH 2048
#define NI 1408
#define NI2 (2 * NI)  // 2816

typedef __attribute__((ext_vector_type(8))) short          bf16x8;
typedef __attribute__((ext_vector_type(8))) unsigned short u16x8;
typedef __attribute__((ext_vector_type(4))) unsigned short u16x4;
typedef __attribute__((ext_vector_type(4))) float          f32x4;

__device__ __forceinline__ unsigned short f2bf(float f) {
  union { float f; uint32_t u; } v; v.f = f;
  uint32_t u = v.u;
  return (unsigned short)((u + 0x7FFFu + ((u >> 16) & 1u)) >> 16);  // RNE
}

// async global->LDS, 16B per lane. LDS dest is wave-uniform base + lane*16.
__device__ __forceinline__ void gload_lds16(const void* g, void* l) {
  __builtin_amdgcn_global_load_lds(
      (const __attribute__((address_space(1))) uint32_t*)g,
      (__attribute__((address_space(3))) uint32_t*)l, 16, 0, 0);
}

#define WAITV0() asm volatile("s_waitcnt vmcnt(0)" ::: "memory")
#define BAR() do { __builtin_amdgcn_sched_barrier(0); \
                   __builtin_amdgcn_s_barrier();      \
                   __builtin_amdgcn_sched_barrier(0); } while (0)

// ---------------------------------------------------------------------------
// x: fp32 -> bf16 elementwise
// ---------------------------------------------------------------------------
__global__ __launch_bounds__(256) void cvt_bf16(const float* __restrict__ src,
                                                unsigned short* __restrict__ dst,
                                                int n8) {
  int i = blockIdx.x * blockDim.x + threadIdx.x;
  const int stride = gridDim.x * blockDim.x;
  for (; i < n8; i += stride) {
    const float4 f0 = ((const float4*)src)[i * 2];
    const float4 f1 = ((const float4*)src)[i * 2 + 1];
    u16x8 o;
    o[0] = f2bf(f0.x); o[1] = f2bf(f0.y); o[2] = f2bf(f0.z); o[3] = f2bf(f0.w);
    o[4] = f2bf(f1.x); o[5] = f2bf(f1.y); o[6] = f2bf(f1.z); o[7] = f2bf(f1.w);
    ((u16x8*)dst)[i] = o;
  }
}

// ---------------------------------------------------------------------------
// Transpose + cvt:  src [E][R][C] f32  ->  dst rows mapped from c, ld = R, bf16
// ilv=1: out row = ((c>>4)<<5) | (c&15) | radd   (16-col gate/up interleave)
// ---------------------------------------------------------------------------
__global__ __launch_bounds__(256) void transpose_cvt(
    const float* __restrict__ src, unsigned short* __restrict__ dst,
    int R, int C, long estride, int ilv, int radd) {
  __shared__ float tile[64][65];
  const int e  = blockIdx.z;
  const int c0 = blockIdx.x * 64;
  const int r0 = blockIdx.y * 64;
  const float* s = src + (size_t)e * R * C;
  unsigned short* d = dst + (size_t)e * estride;
  const int tid = threadIdx.x;
  const int tr  = tid >> 4;        // 0..15
  const int tc  = (tid & 15) * 4;  // 0..60
  #pragma unroll
  for (int it = 0; it < 4; ++it) {
    const int r = it * 16 + tr;
    float4 v = *(const float4*)(s + (size_t)(r0 + r) * C + c0 + tc);
    tile[r][tc + 0] = v.x; tile[r][tc + 1] = v.y;
    tile[r][tc + 2] = v.z; tile[r][tc + 3] = v.w;
  }
  __syncthreads();
  #pragma unroll
  for (int it = 0; it < 4; ++it) {
    const int oc = it * 16 + tr;
    const int c  = c0 + oc;
    const int ro = ilv ? ((((c >> 4) << 5) | (c & 15)) | radd) : c;
    u16x4 o;
    o[0] = f2bf(tile[tc + 0][oc]);
    o[1] = f2bf(tile[tc + 1][oc]);
    o[2] = f2bf(tile[tc + 2][oc]);
    o[3] = f2bf(tile[tc + 3][oc]);
    *(u16x4*)(d + (size_t)ro * R + r0 + tc) = o;
  }
}

// ---------------------------------------------------------------------------
// 8-phase pipelined GEMM (m201-style): C[e,m,n] = A[e,m,:] . B[e,n,:]
// BM=BN=256, BK=64, 512 threads (8 waves, 2M x 4N; wave tile 128x64),
// 2 LDS buffers, 4 phases/K-tile:
//   P1: read A-half0 frags (8) + B nh0 frags (4); stage A(t+1); BAR; 16 MFMA; BAR
//   P2: read B nh1 frags (4);                     stage B(t+1); BAR; 16 MFMA; BAR
//   P3: read A-half1 frags (8);                                 BAR; 16 MFMA; BAR
//   P4: (no reads)                                                   16 MFMA; vmcnt(0); BAR
// t+1's loads issued P1/P2, waited end-P4 (~3 phases in flight, across barriers).
// T2 XOR-swizzle via pre-swizzled global source; T5 setprio around MFMA.
// MODE 0: plain f32 out [E][1024][NBY*256]
// MODE 1: silu-pair bf16 out [E][1024][NBY*128]  (B cols interleaved g16/u16)
// ---------------------------------------------------------------------------
template <int NBY, int KDIM, int MODE>
__global__ __launch_bounds__(512, 2) void gemm_pipe(
    const unsigned short* __restrict__ Ag,  // [E][1024][KDIM]
    const unsigned short* __restrict__ Bg,  // [E][NBY*256][KDIM]
    void* __restrict__ outp) {
  constexpr int KT    = KDIM / 64;
  constexpr int NBLK  = NE * NBY * 4;
  constexpr int CHUNK = NBLK / 8;

  __shared__ __align__(16) unsigned short As[2][256 * 64];
  __shared__ __align__(16) unsigned short Bs[2][256 * 64];

  // XCD-chunked bijective swizzle (per-expert chunks; NBLK % 8 == 0)
  const int flat = blockIdx.x;
  const int orig = (flat & 7) * CHUNK + (flat >> 3);
  const int bx   = orig & 3;          // 4 M-blocks
  const int by   = (orig >> 2) % NBY;
  const int e    = (orig >> 2) / NBY;

  const int bm  = bx * 256;
  const int bnn = by * 256;

  const int tid  = threadIdx.x;
  const int lane = tid & 63;
  const int w    = tid >> 6;
  const int wrm  = (w >> 2) * 128;  // wave M offset (rows)
  const int wcn  = (w & 3) * 64;    // wave N offset (cols)

  const unsigned short* Ae = Ag + (size_t)e * 1024 * KDIM;
  const unsigned short* Be = Bg + (size_t)e * (NBY * 256) * KDIM;

  // staging: wave w stages rows [w*32 + q*8, +8), lane covers row l8, chunk jx
  // (pre-swizzled global source so linear LDS dest + swizzled read match)
  const int l8 = lane >> 3;
  const int jx = (lane & 7) ^ l8;
  const unsigned short* aAg = Ae + (size_t)(bm  + w * 32 + l8) * KDIM + jx * 8;
  const unsigned short* aBg = Be + (size_t)(bnn + w * 32 + l8) * KDIM + jx * 8;

  f32x4 acc[8][4];
  #pragma unroll
  for (int i = 0; i < 8; ++i)
    #pragma unroll
    for (int j = 0; j < 4; ++j) acc[i][j] = f32x4{0.f, 0.f, 0.f, 0.f};

  // swizzled fragment read offset (bytes) within a 16-row frag
  const int aoff = (lane & 15) * 128 + ((((lane >> 4) << 4)) ^ ((lane & 7) << 4));

  auto STAGE_A = [&](unsigned short* dst, int t) {
    const unsigned short* g = aAg + (size_t)t * 64;
    #pragma unroll
    for (int q = 0; q < 4; ++q)
      gload_lds16(g + (size_t)q * 8 * KDIM, dst + (w * 32 + q * 8) * 64);
  };
  auto STAGE_B = [&](unsigned short* dst, int t) {
    const unsigned short* g = aBg + (size_t)t * 64;
    #pragma unroll
    for (int q = 0; q < 4; ++q)
      gload_lds16(g + (size_t)q * 8 * KDIM, dst + (w * 32 + q * 8) * 64);
  };

  unsigned short *Ac = As[0], *Bc = Bs[0], *An = As[1], *Bn = Bs[1];

  // prologue: stage K-tile 0, drain once
  STAGE_A(Ac, 0);
  STAGE_B(Bc, 0);
  WAITV0();
  BAR();

  #pragma unroll 1
  for (int t = 0; t < KT; ++t) {
    const bool st = (t + 1 < KT);
    const char* Ab = (const char*)Ac + wrm * 128;
    const char* Bb = (const char*)Bc + wcn * 128;
    bf16x8 a0[4][2], a1[4][2], b0[2][2], b1[2][2];

    // ---- P1: A-half0 + B nh0 reads; stage A(t+1)
    #pragma unroll
    for (int mi = 0; mi < 4; ++mi) {
      a0[mi][0] = *(const bf16x8*)(Ab + mi * 2048 + aoff);
      a0[mi][1] = *(const bf16x8*)(Ab + mi * 2048 + (aoff ^ 64));
    }
    #pragma unroll
    for (int nj = 0; nj < 2; ++nj) {
      b0[nj][0] = *(const bf16x8*)(Bb + nj * 2048 + aoff);
      b0[nj][1] = *(const bf16x8*)(Bb + nj * 2048 + (aoff ^ 64));
    }
    if (st) STAGE_A(An, t + 1);
    BAR();
    __builtin_amdgcn_s_setprio(1);
    #pragma unroll
    for (int kk = 0; kk < 2; ++kk)
      #pragma unroll
      for (int mi = 0; mi < 4; ++mi)
        #pragma unroll
        for (int nj = 0; nj < 2; ++nj)
          acc[mi][nj] = __builtin_amdgcn_mfma_f32_16x16x32_bf16(
              a0[mi][kk], b0[nj][kk], acc[mi][nj], 0, 0, 0);
    __builtin_amdgcn_s_setprio(0);
    BAR();

    // ---- P2: B nh1 reads; stage B(t+1)
    #pragma unroll
    for (int nj = 0; nj < 2; ++nj) {
      b1[nj][0] = *(const bf16x8*)(Bb + (2 + nj) * 2048 + aoff);
      b1[nj][1] = *(const bf16x8*)(Bb + (2 + nj) * 2048 + (aoff ^ 64));
    }
    if (st) STAGE_B(Bn, t + 1);
    BAR();
    __builtin_amdgcn_s_setprio(1);
    #pragma unroll
    for (int kk = 0; kk < 2; ++kk)
      #pragma unroll
      for (int mi = 0; mi < 4; ++mi)
        #pragma unroll
        for (int nj = 0; nj < 2; ++nj)
          acc[mi][2 + nj] = __builtin_amdgcn_mfma_f32_16x16x32_bf16(
              a0[mi][kk], b1[nj][kk], acc[mi][2 + nj], 0, 0, 0);
    __builtin_amdgcn_s_setprio(0);
    BAR();

    // ---- P3: A-half1 reads
    #pragma unroll
    for (int mi = 0; mi < 4; ++mi) {
      a1[mi][0] = *(const bf16x8*)(Ab + 8192 + mi * 2048 + aoff);
      a1[mi][1] = *(const bf16x8*)(Ab + 8192 + mi * 2048 + (aoff ^ 64));
    }
    BAR();
    __builtin_amdgcn_s_setprio(1);
    #pragma unroll
    for (int kk = 0; kk < 2; ++kk)
      #pragma unroll
      for (int mi = 0; mi < 4; ++mi)
        #pragma unroll
        for (int nj = 0; nj < 2; ++nj)
          acc[4 + mi][2 + nj] = __builtin_amdgcn_mfma_f32_16x16x32_bf16(
              a1[mi][kk], b1[nj][kk], acc[4 + mi][2 + nj], 0, 0, 0);
    __builtin_amdgcn_s_setprio(0);
    BAR();

    // ---- P4: no reads; wait own t+1 stage loads, then K-tile boundary barrier
    __builtin_amdgcn_s_setprio(1);
    #pragma unroll
    for (int kk = 0; kk < 2; ++kk)
      #pragma unroll
      for (int mi = 0; mi < 4; ++mi)
        #pragma unroll
        for (int nj = 0; nj < 2; ++nj)
          acc[4 + mi][nj] = __builtin_amdgcn_mfma_f32_16x16x32_bf16(
              a1[mi][kk], b0[nj][kk], acc[4 + mi][nj], 0, 0, 0);
    __builtin_amdgcn_s_setprio(0);
    if (st) WAITV0();  // loads issued P1/P2, ~3 phases in flight
    BAR();

    unsigned short* tp;
    tp = Ac; Ac = An; An = tp;
    tp = Bc; Bc = Bn; Bn = tp;
  }

  const int crow = (lane >> 4) * 4;
  const int ccol = lane & 15;
  if constexpr (MODE == 0) {
    float* oe = (float*)outp + (size_t)e * 1024 * (NBY * 256);
    #pragma unroll
    for (int mi = 0; mi < 8; ++mi)
      #pragma unroll
      for (int nj = 0; nj < 4; ++nj)
        #pragma unroll
        for (int j = 0; j < 4; ++j) {
          const int row = bm + wrm + mi * 16 + crow + j;
          const int col = bnn + wcn + nj * 16 + ccol;
          oe[(size_t)row * (NBY * 256) + col] = acc[mi][nj][j];
        }
  } else {
    // silu-pair: frag nj=2p is gate cols, nj=2p+1 the matching up cols
    unsigned short* he = (unsigned short*)outp + (size_t)e * 1024 * (NBY * 128);
    const int hcb = by * 128 + (wcn >> 1);
    #pragma unroll
    for (int mi = 0; mi < 8; ++mi)
      #pragma unroll
      for (int p = 0; p < 2; ++p)
        #pragma unroll
        for (int j = 0; j < 4; ++j) {
          const float g = acc[mi][2 * p][j];
          const float u = acc[mi][2 * p + 1][j];
          const float sv = g / (1.0f + __expf(-g)) * u;
          const int row = bm + wrm + mi * 16 + crow + j;
          const int col = hcb + p * 16 + ccol;
          he[(size_t)row * (NBY * 128) + col] = f2bf(sv);
        }
  }
}

// ---------------------------------------------------------------------------
extern "C" void kernel_launch(void* const* d_in, const int* in_sizes, int n_in,
                              void* d_out, int out_size, void* d_ws, size_t ws_size,
                              hipStream_t stream) {
  const float* x    = (const float*)d_in[0];  // [E][T][H]
  const float* gate = (const float*)d_in[1];  // [E][H][I]
  const float* up   = (const float*)d_in[2];  // [E][H][I]
  const float* down = (const float*)d_in[3];  // [E][I][H]
  float* out = (float*)d_out;                 // [E][T][H]

  // workspace (bf16 elems): x_bf [E][T][H], wcat [E][2I][H] (interleaved 16-col
  // gate/up), dT [E][H][I], h [E][T][I].
  unsigned short* x_bf = (unsigned short*)d_ws;
  unsigned short* wcat = x_bf + (size_t)NE * NT * NH;
  unsigned short* dT   = wcat + (size_t)NE * NI2 * NH;
  unsigned short* hb   = dT   + (size_t)NE * NH * NI;

  cvt_bf16<<<2048, 256, 0, stream>>>(x, x_bf, NE * NT * NH / 8);

  transpose_cvt<<<dim3(NI / 64, NH / 64, NE), 256, 0, stream>>>(
      gate, wcat, NH, NI, (long)NI2 * NH, 1, 0);
  transpose_cvt<<<dim3(NI / 64, NH / 64, NE), 256, 0, stream>>>(
      up, wcat, NH, NI, (long)NI2 * NH, 1, 16);
  transpose_cvt<<<dim3(NH / 64, NI / 64, NE), 256, 0, stream>>>(
      down, dT, NI, NH, (long)NH * NI, 0, 0);

  // GEMM1: [1024 x 2816] = x_bf @ wcat^T, fused silu-pair -> h bf16
  gemm_pipe<11, NH, 1><<<NE * 11 * 4, 512, 0, stream>>>(x_bf, wcat, hb);
  // GEMM2: [1024 x 2048] = h @ dT^T -> out f32
  gemm_pipe<8, NI, 0><<<NE * 8 * 4, 512, 0, stream>>>(hb, dT, out);
}